// Round 10
// baseline (533.621 us; speedup 1.0000x reference)
//
#include <hip/hip_runtime.h>

// ---------------------------------------------------------------------------
// SelfAttention forward (N=2, L=2048, E=1024, H=16, D=64), f32 in/out.
// Outputs concatenated: out | q | k | v | energy | attention
//
// Round-10 structure (5 launches):
//  0) cvt7: weights + inputs -> bf16.
//  1) qkv projections (m97-style GEMM, grid.z=3); k dual-writes kb bf16.
//  2) transpose vf f32 -> vt bf16 [nh][d][l].
//  3) attn_fused2_k: ONE kernel, per-block {phase A: compute-only
//     tau-permuted QK^T+exp+PV over 2048 cols -> inv in REGISTERS + head;
//     phase B: streaming QK^T recompute -> 16KB swizzled LDS stage ->
//     1KB-contiguous NT stores of energy and attention}. Resident blocks
//     de-phase -> phase-A loads/MFMA overlap phase-B stores across blocks.
//     4096 blocks x 64 thr (16 q-rows each), XCD-swizzled.
//  4) out-projection: 128x64-tile GEMM (512 blocks).
// No max subtraction: |S| <~ 16 -> exp(S/8) <= e^2, f32-safe.
// ---------------------------------------------------------------------------

typedef __attribute__((ext_vector_type(8))) short     s16x8;   // 8 bf16
typedef __attribute__((ext_vector_type(4))) float     f32x4;
typedef __attribute__((ext_vector_type(8))) unsigned short u16x8;
typedef __attribute__((ext_vector_type(4))) unsigned short u16x4;

#define DEVINL __device__ __forceinline__

DEVINL unsigned short f2b(float f) {           // f32 -> bf16 (RNE)
  unsigned int u = __builtin_bit_cast(unsigned int, f);
  u = (u + 0x7FFFu + ((u >> 16) & 1u)) >> 16;
  return (unsigned short)u;
}

DEVINL s16x8 pack8(float4 a, float4 b) {
  s16x8 r;
  r[0] = (short)f2b(a.x); r[1] = (short)f2b(a.y);
  r[2] = (short)f2b(a.z); r[3] = (short)f2b(a.w);
  r[4] = (short)f2b(b.x); r[5] = (short)f2b(b.y);
  r[6] = (short)f2b(b.z); r[7] = (short)f2b(b.w);
  return r;
}

DEVINL f32x4 mfma16(s16x8 a, s16x8 b, f32x4 c) {
  return __builtin_amdgcn_mfma_f32_16x16x32_bf16(a, b, c, 0, 0, 0);
}

DEVINL void gload16(const void* g, void* l) {  // 16B global -> LDS direct
  __builtin_amdgcn_global_load_lds(
      (const __attribute__((address_space(1))) void*)g,
      (__attribute__((address_space(3))) void*)l, 16, 0, 0);
}

// ---------------------------------------------------------------------------
// 7 f32->bf16 converts in one launch. grid (2048, 7).
// ---------------------------------------------------------------------------
__global__ __launch_bounds__(256) void cvt7_k(
    const float* __restrict__ w0, const float* __restrict__ w1,
    const float* __restrict__ w2, const float* __restrict__ w3,
    const float* __restrict__ x0, const float* __restrict__ x1,
    const float* __restrict__ x2, unsigned short* __restrict__ dw,
    unsigned short* __restrict__ dwo, unsigned short* __restrict__ dx) {
  int z = blockIdx.y;
  const float* s;
  unsigned short* d;
  int n;
  if (z < 3)      { s = (z == 0) ? w0 : (z == 1) ? w1 : w2;
                    d = dw + (size_t)z * 1048576; n = 1048576; }
  else if (z == 3){ s = w3; d = dwo; n = 1048576; }
  else            { s = (z == 4) ? x0 : (z == 5) ? x1 : x2;
                    d = dx + (size_t)(z - 4) * 4194304; n = 4194304; }
  int i = (blockIdx.x * 256 + threadIdx.x) * 8;
  if (i < n) {
    float4 a = *(const float4*)(s + i);
    float4 b = *(const float4*)(s + i + 4);
    u16x8 o;
    o[0] = f2b(a.x); o[1] = f2b(a.y); o[2] = f2b(a.z); o[3] = f2b(a.w);
    o[4] = f2b(b.x); o[5] = f2b(b.y); o[6] = f2b(b.z); o[7] = f2b(b.w);
    *(u16x8*)(d + i) = o;
  }
}

// ---------------------------------------------------------------------------
// m97-style NT GEMM, 128x128 tile (q/k/v projections).
// ---------------------------------------------------------------------------
template<bool QKV>
__global__ __launch_bounds__(256) void gemm_bt(
    const unsigned short* __restrict__ Ab, const unsigned short* __restrict__ Bb,
    const float* __restrict__ b0, const float* __restrict__ b1,
    const float* __restrict__ b2, float* __restrict__ Cf,
    unsigned short* __restrict__ Cb) {
  __shared__ unsigned short lA[4096];   // [128][32] bf16, linear
  __shared__ unsigned short lB[4096];
  int z = QKV ? blockIdx.z : 0;
  const unsigned short* A = Ab + (size_t)z * 4194304;
  const unsigned short* B = Bb + (size_t)z * 1048576;
  const float* bias = (z == 0) ? b0 : (z == 1) ? b1 : b2;
  float* C = Cf + (size_t)z * 4194304;
  unsigned short* Cw = (QKV && z == 1) ? Cb : nullptr;

  int t = threadIdx.x, lane = t & 63, w = t >> 6;
  int m0 = blockIdx.y * 128, n0 = blockIdx.x * 128;
  int wm = (w >> 1) * 64, wn = (w & 1) * 64;
  int lr = lane & 15, g = lane >> 4, kg = g * 8, rb = g * 4;

  int srow = t >> 2, scol = (t & 3) * 8;
  const unsigned short* gA = A + (size_t)(m0 + srow) * 1024 + scol;
  const unsigned short* gB = B + (size_t)(n0 + srow) * 1024 + scol;
  unsigned short* dA = lA + w * 512;
  unsigned short* dB = lB + w * 512;

  f32x4 acc[4][4] = {};

  for (int k0 = 0; k0 < 1024; k0 += 32) {
    gload16(gA,             dA);
    gload16(gA + 64 * 1024, dA + 2048);
    gload16(gB,             dB);
    gload16(gB + 64 * 1024, dB + 2048);
    gA += 32; gB += 32;
    __syncthreads();
    s16x8 af[4], bf[4];
    #pragma unroll
    for (int i = 0; i < 4; i++)
      af[i] = *(const s16x8*)&lA[(wm + i * 16 + lr) * 32 + kg];
    #pragma unroll
    for (int j = 0; j < 4; j++)
      bf[j] = *(const s16x8*)&lB[(wn + j * 16 + lr) * 32 + kg];
    #pragma unroll
    for (int i = 0; i < 4; i++)
      #pragma unroll
      for (int j = 0; j < 4; j++)
        acc[i][j] = mfma16(af[i], bf[j], acc[i][j]);
    __syncthreads();
  }

  #pragma unroll
  for (int i = 0; i < 4; i++) {
    #pragma unroll
    for (int j = 0; j < 4; j++) {
      int col = n0 + wn + j * 16 + lr;
      float bv = bias[col];
      #pragma unroll
      for (int r = 0; r < 4; r++) {
        int row = m0 + wm + i * 16 + rb + r;
        float v = acc[i][j][r] + bv;
        size_t idx = (size_t)row * 1024 + col;
        C[idx] = v;
        if (Cw) Cw[idx] = f2b(v);
      }
    }
  }
}

// ---------------------------------------------------------------------------
// 128x64-tile GEMM for the out-projection: grid (16,32) = 512 blocks.
// ---------------------------------------------------------------------------
__global__ __launch_bounds__(256) void gemm_bt64(
    const unsigned short* __restrict__ Ab, const unsigned short* __restrict__ Bb,
    const float* __restrict__ bias, float* __restrict__ Cf) {
  __shared__ unsigned short lA[4096];   // [128][32]
  __shared__ unsigned short lB[2048];   // [64][32]
  int t = threadIdx.x, lane = t & 63, w = t >> 6;
  int m0 = blockIdx.y * 128, n0 = blockIdx.x * 64;
  int wm = (w >> 1) * 64, wn = (w & 1) * 32;
  int lr = lane & 15, g = lane >> 4, kg = g * 8, rb = g * 4;

  int srow = t >> 2, scol = (t & 3) * 8;
  unsigned short* dA = lA + w * 512;
  unsigned short* dB = lB + w * 512;

  const unsigned short* gA = Ab + (size_t)(m0 + srow) * 1024 + scol;
  const unsigned short* gB = Bb + (size_t)(n0 + srow) * 1024 + scol;
  f32x4 acc[4][2] = {};
  for (int k0 = 0; k0 < 1024; k0 += 32) {
    gload16(gA,             dA);
    gload16(gA + 64 * 1024, dA + 2048);
    gload16(gB,             dB);
    gA += 32; gB += 32;
    __syncthreads();
    s16x8 af[4], bf[2];
    #pragma unroll
    for (int i = 0; i < 4; i++)
      af[i] = *(const s16x8*)&lA[(wm + i * 16 + lr) * 32 + kg];
    #pragma unroll
    for (int j = 0; j < 2; j++)
      bf[j] = *(const s16x8*)&lB[(wn + j * 16 + lr) * 32 + kg];
    #pragma unroll
    for (int i = 0; i < 4; i++)
      #pragma unroll
      for (int j = 0; j < 2; j++)
        acc[i][j] = mfma16(af[i], bf[j], acc[i][j]);
    __syncthreads();
  }
  #pragma unroll
  for (int i = 0; i < 4; i++) {
    #pragma unroll
    for (int j = 0; j < 2; j++) {
      int col = n0 + wn + j * 16 + lr;
      float bv = bias[col];
      #pragma unroll
      for (int r = 0; r < 4; r++) {
        int row = m0 + wm + i * 16 + rb + r;
        Cf[(size_t)row * 1024 + col] = acc[i][j][r] + bv;
      }
    }
  }
}

// ---------------------------------------------------------------------------
// v (f32, [n][l][h*64+d]) -> vt (bf16, [n*16+h][d][l])  (unchanged)
// ---------------------------------------------------------------------------
__global__ __launch_bounds__(256) void transpose_v_k(
    const float* __restrict__ vf, unsigned short* __restrict__ vt) {
  __shared__ unsigned short tile[64][72];
  int nh = blockIdx.y, n = nh >> 4, h = nh & 15;
  int l0 = blockIdx.x * 64;
  int t = threadIdx.x;
  int lr = t >> 2;
  int dc = (t & 3) * 16;
  const float* src = vf + ((size_t)(n * 2048 + l0 + lr)) * 1024 + h * 64 + dc;
  float4 a = *(const float4*)(src);
  float4 b = *(const float4*)(src + 4);
  float4 c = *(const float4*)(src + 8);
  float4 e = *(const float4*)(src + 12);
  float vals[16] = {a.x, a.y, a.z, a.w, b.x, b.y, b.z, b.w,
                    c.x, c.y, c.z, c.w, e.x, e.y, e.z, e.w};
  #pragma unroll
  for (int j = 0; j < 16; j++) tile[dc + j][lr] = f2b(vals[j]);
  __syncthreads();
  int dr = t >> 2;
  int lc = (t & 3) * 16;
  unsigned short* dst = vt + ((size_t)nh * 64 + dr) * 2048 + l0 + lc;
  *(u16x8*)(dst)     = *(const u16x8*)&tile[dr][lc];
  *(u16x8*)(dst + 8) = *(const u16x8*)&tile[dr][lc + 8];
}

// ---------------------------------------------------------------------------
// attn_fused2_k: merged compute+store attention. 4096 blocks x 64 thr,
// block = (nh, 16 q-rows). Phase A: tau-permuted zero-LDS swapped QK^T +
// exp + PV + row-sums (round-9 attn_pv math); inv stays in registers.
// Phase B: streaming QK^T recompute -> 16KB swizzled stage -> 1KB NT stores
// of energy and attention (round-9 attn_store math, invs from registers).
// ---------------------------------------------------------------------------
__global__ __launch_bounds__(64) void attn_fused2_k(
    const float* __restrict__ qf, const unsigned short* __restrict__ kb,
    const unsigned short* __restrict__ vt, float* __restrict__ energy,
    float* __restrict__ attn, unsigned short* __restrict__ head) {
  __shared__ float stage[4096];              // 16 x 256 f32 = 16KB
  int bid = blockIdx.x;
  int cid = (bid & 7) * 512 + (bid >> 3);    // XCD-contiguous remap (4096/8)
  int nh = cid >> 7, qt = cid & 127;
  int n = nh >> 4, h = nh & 15;
  int q0 = qt * 16;
  int lane = threadIdx.x;
  int lr = lane & 15, g = lane >> 4, kg = g * 8, rb = g * 4;
  int kbase = ((lr >> 2) << 3) + (lr & 3);   // tau's lane-row component

  const float* qrow = qf + ((size_t)(n * 2048 + q0 + lr)) * 1024 + h * 64;
  s16x8 bq0 = pack8(*(const float4*)(qrow + kg), *(const float4*)(qrow + kg + 4));
  s16x8 bq1 = pack8(*(const float4*)(qrow + 32 + kg),
                    *(const float4*)(qrow + 32 + kg + 4));

  const unsigned short* Kb = kb + (size_t)n * (2048 * 1024) + h * 64;
  const unsigned short* Vb = vt + (size_t)nh * (64 * 2048);

  // ---- phase A: compute-only PV + row sums (no big stores) ----
  float lsum = 0.f;
  f32x4 acc_o[4] = {};
  for (int c0 = 0; c0 < 2048; c0 += 64) {
    s16x8 vv0[4], vv1[4];
    #pragma unroll
    for (int nf = 0; nf < 4; nf++) {
      const unsigned short* vp = Vb + (size_t)(nf * 16 + lr) * 2048 + c0 + kg;
      vv0[nf] = *(const s16x8*)(vp);
      vv1[nf] = *(const s16x8*)(vp + 32);
    }
    f32x4 s[4];
    #pragma unroll
    for (int jk = 0; jk < 4; jk++) {
      int kr = c0 + ((jk >> 1) << 5) + ((jk & 1) << 2) + kbase;
      const unsigned short* kp = Kb + (size_t)kr * 1024 + kg;
      s16x8 a0 = *(const s16x8*)kp;
      s16x8 a1 = *(const s16x8*)(kp + 32);
      f32x4 z = {};
      z = mfma16(a0, bq0, z);
      s[jk] = mfma16(a1, bq1, z);
    }
    float e[4][4];
    #pragma unroll
    for (int jk = 0; jk < 4; jk++)
      #pragma unroll
      for (int r = 0; r < 4; r++) {
        e[jk][r] = __expf(s[jk][r] * 0.125f);
        lsum += e[jk][r];
      }
    s16x8 pa0, pa1;
    #pragma unroll
    for (int r = 0; r < 4; r++) {
      pa0[r]     = (short)f2b(e[0][r]);
      pa0[r + 4] = (short)f2b(e[1][r]);
      pa1[r]     = (short)f2b(e[2][r]);
      pa1[r + 4] = (short)f2b(e[3][r]);
    }
    #pragma unroll
    for (int nf = 0; nf < 4; nf++) {
      acc_o[nf] = mfma16(pa0, vv0[nf], acc_o[nf]);
      acc_o[nf] = mfma16(pa1, vv1[nf], acc_o[nf]);
    }
  }

  // row sum for q = q0+lr (4 lanes share lr); inv stays in registers
  lsum += __shfl_xor(lsum, 16);
  lsum += __shfl_xor(lsum, 32);
  float inv = 1.0f / lsum;
  float invr[4];
  #pragma unroll
  for (int r = 0; r < 4; r++) invr[r] = __shfl(inv, rb + r);

  // head = O / l  (bf16); acc_o rows q = rb+r, cols d = nf*16+lr
  unsigned short* hrow = head + ((size_t)(n * 2048 + q0)) * 1024 + h * 64;
  #pragma unroll
  for (int nf = 0; nf < 4; nf++)
    #pragma unroll
    for (int r = 0; r < 4; r++)
      hrow[(size_t)(rb + r) * 1024 + nf * 16 + lr] = f2b(acc_o[nf][r] * invr[r]);

  // ---- phase B: streaming energy + attention stores ----
  float* eblk = energy + (size_t)nh * (2048ull * 2048ull) + (size_t)q0 * 2048;
  float* ablk = attn + (size_t)nh * (2048ull * 2048ull) + (size_t)q0 * 2048;

  for (int c0 = 0; c0 < 2048; c0 += 256) {
    // fill stage: 4 chunks x 4 jk, C-layout -> swizzled [row][col]
    #pragma unroll
    for (int cc = 0; cc < 4; cc++) {
      #pragma unroll
      for (int jk = 0; jk < 4; jk++) {
        const unsigned short* kp =
            Kb + (size_t)(c0 + cc * 64 + jk * 16 + lr) * 1024 + kg;
        s16x8 a0 = *(const s16x8*)kp;
        s16x8 a1 = *(const s16x8*)(kp + 32);
        f32x4 z = {};
        z = mfma16(a0, bq0, z);
        f32x4 s = mfma16(a1, bq1, z);
        int col = cc * 64 + jk * 16 + rb;            // logical col (4-aligned)
        *(f32x4*)&stage[lr * 256 + (col ^ ((lr & 7) << 2))] = s;
      }
    }
    __syncthreads();   // lgkm drain before re-read (1 wave: cheap)
    // dump: row i, lane L covers cols 4L..4L+3 -> 1KB contiguous per store
    #pragma unroll
    for (int i = 0; i < 16; i++) {
      f32x4 ev = *(const f32x4*)&stage[i * 256 + ((lane * 4) ^ ((i & 7) << 2))];
      __builtin_nontemporal_store(
          ev, (f32x4*)(eblk + (size_t)i * 2048 + c0 + lane * 4));
      float iv = __shfl(inv, i);
      f32x4 av;
      av[0] = __expf(ev[0] * 0.125f) * iv;
      av[1] = __expf(ev[1] * 0.125f) * iv;
      av[2] = __expf(ev[2] * 0.125f) * iv;
      av[3] = __expf(ev[3] * 0.125f) * iv;
      __builtin_nontemporal_store(
          av, (f32x4*)(ablk + (size_t)i * 2048 + c0 + lane * 4));
    }
    __syncthreads();   // stage reuse guard
  }
}

// ---------------------------------------------------------------------------
extern "C" void kernel_launch(void* const* d_in, const int* in_sizes, int n_in,
                              void* d_out, int out_size, void* d_ws, size_t ws_size,
                              hipStream_t stream) {
  const float* Vin = (const float*)d_in[0];
  const float* Kin = (const float*)d_in[1];
  const float* Qin = (const float*)d_in[2];
  const float* Wq  = (const float*)d_in[3];
  const float* bq  = (const float*)d_in[4];
  const float* Wk  = (const float*)d_in[5];
  const float* bk  = (const float*)d_in[6];
  const float* Wv  = (const float*)d_in[7];
  const float* bv  = (const float*)d_in[8];
  const float* Wo  = (const float*)d_in[9];
  const float* bo  = (const float*)d_in[10];

  float* out    = (float*)d_out;
  float* qf     = out + 4194304;          // (4096,1024) f32; kf,vf follow
  float* energy = out + 16777216;         // (2,16,2048,2048) f32
  float* attn   = out + 150994944;

  unsigned short* vt = (unsigned short*)out;            // [nh][64][2048]
  unsigned short* kb = (unsigned short*)out + 4194304;
  unsigned short* wqkv = (unsigned short*)energy;
  unsigned short* xqkv = (unsigned short*)(energy + 2097152);
  // d_ws: head bf16 (8MB) + wob bf16 (2MB)
  unsigned short* head = (unsigned short*)d_ws;
  unsigned short* wob  = head + 4194304;

  cvt7_k<<<dim3(2048, 7), 256, 0, stream>>>(
      Wq, Wk, Wv, Wo, Qin, Kin, Vin, wqkv, wob, xqkv);

  gemm_bt<true><<<dim3(8, 32, 3), 256, 0, stream>>>(
      xqkv, wqkv, bq, bk, bv, qf, kb);

  transpose_v_k<<<dim3(32, 32), 256, 0, stream>>>(qf + 8388608, vt);

  attn_fused2_k<<<dim3(4096), 64, 0, stream>>>(qf, kb, vt, energy, attn, head);

  gemm_bt64<<<dim3(16, 32), 256, 0, stream>>>(head, wob, bo, out);
}

// Round 11
// 474.373 us; speedup vs baseline: 1.1249x; 1.1249x over previous
//
#include <hip/hip_runtime.h>

// ---------------------------------------------------------------------------
// SelfAttention forward (N=2, L=2048, E=1024, H=16, D=64), f32 in/out.
// Outputs concatenated: out | q | k | v | energy | attention
//
// Round-11 structure (5 launches):
//  0) cvt7: weights + inputs -> bf16.
//  1) qkv projections (m97-style GEMM, grid.z=3); k dual-writes kb bf16.
//  2) transpose vf f32 -> vt bf16 [nh][d][l].
//  3) attn_fused3_k: 1024 blocks x 256 thr (4 waves), wave-private
//     everything, ZERO barriers.
//     Phase A: tau-permuted zero-LDS swapped QK^T + exp + PV + row sums
//       (rounds 8-10 verified); inv stays in registers; head bf16 out.
//     Phase B (per 64-col round, vmcnt-FIFO-ordered):
//       1. issue this round's K loads
//       2. NT-store PREVIOUS round's energy+attention from registers
//          (younger than the loads -> MFMA's load wait never drains stores)
//       3. MFMA -> s (C-layout)
//       4. wave-private 4KB stage write (bijective XOR swizzle)
//       5. extract rows to registers (256B-segment store layout)
//     No __syncthreads anywhere (wave-private LDS: lgkmcnt only).
//  4) out-projection: 128x64-tile GEMM (512 blocks).
// No max subtraction: |S| <~ 16 -> exp(S/8) <= e^2, f32-safe.
// ---------------------------------------------------------------------------

typedef __attribute__((ext_vector_type(8))) short     s16x8;   // 8 bf16
typedef __attribute__((ext_vector_type(4))) float     f32x4;
typedef __attribute__((ext_vector_type(8))) unsigned short u16x8;
typedef __attribute__((ext_vector_type(4))) unsigned short u16x4;

#define DEVINL __device__ __forceinline__

DEVINL unsigned short f2b(float f) {           // f32 -> bf16 (RNE)
  unsigned int u = __builtin_bit_cast(unsigned int, f);
  u = (u + 0x7FFFu + ((u >> 16) & 1u)) >> 16;
  return (unsigned short)u;
}

DEVINL s16x8 pack8(float4 a, float4 b) {
  s16x8 r;
  r[0] = (short)f2b(a.x); r[1] = (short)f2b(a.y);
  r[2] = (short)f2b(a.z); r[3] = (short)f2b(a.w);
  r[4] = (short)f2b(b.x); r[5] = (short)f2b(b.y);
  r[6] = (short)f2b(b.z); r[7] = (short)f2b(b.w);
  return r;
}

DEVINL f32x4 mfma16(s16x8 a, s16x8 b, f32x4 c) {
  return __builtin_amdgcn_mfma_f32_16x16x32_bf16(a, b, c, 0, 0, 0);
}

DEVINL void gload16(const void* g, void* l) {  // 16B global -> LDS direct
  __builtin_amdgcn_global_load_lds(
      (const __attribute__((address_space(1))) void*)g,
      (__attribute__((address_space(3))) void*)l, 16, 0, 0);
}

// ---------------------------------------------------------------------------
// 7 f32->bf16 converts in one launch. grid (2048, 7).
// ---------------------------------------------------------------------------
__global__ __launch_bounds__(256) void cvt7_k(
    const float* __restrict__ w0, const float* __restrict__ w1,
    const float* __restrict__ w2, const float* __restrict__ w3,
    const float* __restrict__ x0, const float* __restrict__ x1,
    const float* __restrict__ x2, unsigned short* __restrict__ dw,
    unsigned short* __restrict__ dwo, unsigned short* __restrict__ dx) {
  int z = blockIdx.y;
  const float* s;
  unsigned short* d;
  int n;
  if (z < 3)      { s = (z == 0) ? w0 : (z == 1) ? w1 : w2;
                    d = dw + (size_t)z * 1048576; n = 1048576; }
  else if (z == 3){ s = w3; d = dwo; n = 1048576; }
  else            { s = (z == 4) ? x0 : (z == 5) ? x1 : x2;
                    d = dx + (size_t)(z - 4) * 4194304; n = 4194304; }
  int i = (blockIdx.x * 256 + threadIdx.x) * 8;
  if (i < n) {
    float4 a = *(const float4*)(s + i);
    float4 b = *(const float4*)(s + i + 4);
    u16x8 o;
    o[0] = f2b(a.x); o[1] = f2b(a.y); o[2] = f2b(a.z); o[3] = f2b(a.w);
    o[4] = f2b(b.x); o[5] = f2b(b.y); o[6] = f2b(b.z); o[7] = f2b(b.w);
    *(u16x8*)(d + i) = o;
  }
}

// ---------------------------------------------------------------------------
// m97-style NT GEMM, 128x128 tile (q/k/v projections).
// ---------------------------------------------------------------------------
template<bool QKV>
__global__ __launch_bounds__(256) void gemm_bt(
    const unsigned short* __restrict__ Ab, const unsigned short* __restrict__ Bb,
    const float* __restrict__ b0, const float* __restrict__ b1,
    const float* __restrict__ b2, float* __restrict__ Cf,
    unsigned short* __restrict__ Cb) {
  __shared__ unsigned short lA[4096];   // [128][32] bf16, linear
  __shared__ unsigned short lB[4096];
  int z = QKV ? blockIdx.z : 0;
  const unsigned short* A = Ab + (size_t)z * 4194304;
  const unsigned short* B = Bb + (size_t)z * 1048576;
  const float* bias = (z == 0) ? b0 : (z == 1) ? b1 : b2;
  float* C = Cf + (size_t)z * 4194304;
  unsigned short* Cw = (QKV && z == 1) ? Cb : nullptr;

  int t = threadIdx.x, lane = t & 63, w = t >> 6;
  int m0 = blockIdx.y * 128, n0 = blockIdx.x * 128;
  int wm = (w >> 1) * 64, wn = (w & 1) * 64;
  int lr = lane & 15, g = lane >> 4, kg = g * 8, rb = g * 4;

  int srow = t >> 2, scol = (t & 3) * 8;
  const unsigned short* gA = A + (size_t)(m0 + srow) * 1024 + scol;
  const unsigned short* gB = B + (size_t)(n0 + srow) * 1024 + scol;
  unsigned short* dA = lA + w * 512;
  unsigned short* dB = lB + w * 512;

  f32x4 acc[4][4] = {};

  for (int k0 = 0; k0 < 1024; k0 += 32) {
    gload16(gA,             dA);
    gload16(gA + 64 * 1024, dA + 2048);
    gload16(gB,             dB);
    gload16(gB + 64 * 1024, dB + 2048);
    gA += 32; gB += 32;
    __syncthreads();
    s16x8 af[4], bf[4];
    #pragma unroll
    for (int i = 0; i < 4; i++)
      af[i] = *(const s16x8*)&lA[(wm + i * 16 + lr) * 32 + kg];
    #pragma unroll
    for (int j = 0; j < 4; j++)
      bf[j] = *(const s16x8*)&lB[(wn + j * 16 + lr) * 32 + kg];
    #pragma unroll
    for (int i = 0; i < 4; i++)
      #pragma unroll
      for (int j = 0; j < 4; j++)
        acc[i][j] = mfma16(af[i], bf[j], acc[i][j]);
    __syncthreads();
  }

  #pragma unroll
  for (int i = 0; i < 4; i++) {
    #pragma unroll
    for (int j = 0; j < 4; j++) {
      int col = n0 + wn + j * 16 + lr;
      float bv = bias[col];
      #pragma unroll
      for (int r = 0; r < 4; r++) {
        int row = m0 + wm + i * 16 + rb + r;
        float v = acc[i][j][r] + bv;
        size_t idx = (size_t)row * 1024 + col;
        C[idx] = v;
        if (Cw) Cw[idx] = f2b(v);
      }
    }
  }
}

// ---------------------------------------------------------------------------
// 128x64-tile GEMM for the out-projection: grid (16,32) = 512 blocks.
// ---------------------------------------------------------------------------
__global__ __launch_bounds__(256) void gemm_bt64(
    const unsigned short* __restrict__ Ab, const unsigned short* __restrict__ Bb,
    const float* __restrict__ bias, float* __restrict__ Cf) {
  __shared__ unsigned short lA[4096];   // [128][32]
  __shared__ unsigned short lB[2048];   // [64][32]
  int t = threadIdx.x, lane = t & 63, w = t >> 6;
  int m0 = blockIdx.y * 128, n0 = blockIdx.x * 64;
  int wm = (w >> 1) * 64, wn = (w & 1) * 32;
  int lr = lane & 15, g = lane >> 4, kg = g * 8, rb = g * 4;

  int srow = t >> 2, scol = (t & 3) * 8;
  unsigned short* dA = lA + w * 512;
  unsigned short* dB = lB + w * 512;

  const unsigned short* gA = Ab + (size_t)(m0 + srow) * 1024 + scol;
  const unsigned short* gB = Bb + (size_t)(n0 + srow) * 1024 + scol;
  f32x4 acc[4][2] = {};
  for (int k0 = 0; k0 < 1024; k0 += 32) {
    gload16(gA,             dA);
    gload16(gA + 64 * 1024, dA + 2048);
    gload16(gB,             dB);
    gA += 32; gB += 32;
    __syncthreads();
    s16x8 af[4], bf[2];
    #pragma unroll
    for (int i = 0; i < 4; i++)
      af[i] = *(const s16x8*)&lA[(wm + i * 16 + lr) * 32 + kg];
    #pragma unroll
    for (int j = 0; j < 2; j++)
      bf[j] = *(const s16x8*)&lB[(wn + j * 16 + lr) * 32 + kg];
    #pragma unroll
    for (int i = 0; i < 4; i++)
      #pragma unroll
      for (int j = 0; j < 2; j++)
        acc[i][j] = mfma16(af[i], bf[j], acc[i][j]);
    __syncthreads();
  }
  #pragma unroll
  for (int i = 0; i < 4; i++) {
    #pragma unroll
    for (int j = 0; j < 2; j++) {
      int col = n0 + wn + j * 16 + lr;
      float bv = bias[col];
      #pragma unroll
      for (int r = 0; r < 4; r++) {
        int row = m0 + wm + i * 16 + rb + r;
        Cf[(size_t)row * 1024 + col] = acc[i][j][r] + bv;
      }
    }
  }
}

// ---------------------------------------------------------------------------
// v (f32, [n][l][h*64+d]) -> vt (bf16, [n*16+h][d][l])  (unchanged)
// ---------------------------------------------------------------------------
__global__ __launch_bounds__(256) void transpose_v_k(
    const float* __restrict__ vf, unsigned short* __restrict__ vt) {
  __shared__ unsigned short tile[64][72];
  int nh = blockIdx.y, n = nh >> 4, h = nh & 15;
  int l0 = blockIdx.x * 64;
  int t = threadIdx.x;
  int lr = t >> 2;
  int dc = (t & 3) * 16;
  const float* src = vf + ((size_t)(n * 2048 + l0 + lr)) * 1024 + h * 64 + dc;
  float4 a = *(const float4*)(src);
  float4 b = *(const float4*)(src + 4);
  float4 c = *(const float4*)(src + 8);
  float4 e = *(const float4*)(src + 12);
  float vals[16] = {a.x, a.y, a.z, a.w, b.x, b.y, b.z, b.w,
                    c.x, c.y, c.z, c.w, e.x, e.y, e.z, e.w};
  #pragma unroll
  for (int j = 0; j < 16; j++) tile[dc + j][lr] = f2b(vals[j]);
  __syncthreads();
  int dr = t >> 2;
  int lc = (t & 3) * 16;
  unsigned short* dst = vt + ((size_t)nh * 64 + dr) * 2048 + l0 + lc;
  *(u16x8*)(dst)     = *(const u16x8*)&tile[dr][lc];
  *(u16x8*)(dst + 8) = *(const u16x8*)&tile[dr][lc + 8];
}

// ---------------------------------------------------------------------------
// attn_fused3_k: 1024 blocks x 256 thr (4 waves). Wave w owns q-rows
// q0+w*16 .. +15 end-to-end; everything wave-private; NO barriers.
// ---------------------------------------------------------------------------
__global__ __launch_bounds__(256, 4) void attn_fused3_k(
    const float* __restrict__ qf, const unsigned short* __restrict__ kb,
    const unsigned short* __restrict__ vt, float* __restrict__ energy,
    float* __restrict__ attn, unsigned short* __restrict__ head) {
  __shared__ float stage[4][1024];           // 4KB per wave
  int bid = blockIdx.x;
  int cid = (bid & 7) * 128 + (bid >> 3);    // XCD-contiguous remap (1024/8)
  int nh = cid >> 5, qt = cid & 31;
  int n = nh >> 4, h = nh & 15;
  int t = threadIdx.x, w = t >> 6, lane = t & 63;
  int q0 = qt * 64, wrow = w * 16;
  int lr = lane & 15, g = lane >> 4, kg = g * 8, rb = g * 4;
  int kbase = ((lr >> 2) << 3) + (lr & 3);   // tau's lane-row component

  const float* qrow = qf + ((size_t)(n * 2048 + q0 + wrow + lr)) * 1024 + h * 64;
  s16x8 bq0 = pack8(*(const float4*)(qrow + kg), *(const float4*)(qrow + kg + 4));
  s16x8 bq1 = pack8(*(const float4*)(qrow + 32 + kg),
                    *(const float4*)(qrow + 32 + kg + 4));

  const unsigned short* Kb = kb + (size_t)n * (2048 * 1024) + h * 64;
  const unsigned short* Vb = vt + (size_t)nh * (64 * 2048);

  // ---- phase A: compute-only PV + row sums (tau-permuted, no big stores) ----
  float lsum = 0.f;
  f32x4 acc_o[4] = {};
  for (int c0 = 0; c0 < 2048; c0 += 64) {
    s16x8 vv0[4], vv1[4];
    #pragma unroll
    for (int nf = 0; nf < 4; nf++) {
      const unsigned short* vp = Vb + (size_t)(nf * 16 + lr) * 2048 + c0 + kg;
      vv0[nf] = *(const s16x8*)(vp);
      vv1[nf] = *(const s16x8*)(vp + 32);
    }
    f32x4 s[4];
    #pragma unroll
    for (int jk = 0; jk < 4; jk++) {
      int kr = c0 + ((jk >> 1) << 5) + ((jk & 1) << 2) + kbase;
      const unsigned short* kp = Kb + (size_t)kr * 1024 + kg;
      s16x8 a0 = *(const s16x8*)kp;
      s16x8 a1 = *(const s16x8*)(kp + 32);
      f32x4 z = {};
      z = mfma16(a0, bq0, z);
      s[jk] = mfma16(a1, bq1, z);
    }
    float e[4][4];
    #pragma unroll
    for (int jk = 0; jk < 4; jk++)
      #pragma unroll
      for (int r = 0; r < 4; r++) {
        e[jk][r] = __expf(s[jk][r] * 0.125f);
        lsum += e[jk][r];
      }
    s16x8 pa0, pa1;
    #pragma unroll
    for (int r = 0; r < 4; r++) {
      pa0[r]     = (short)f2b(e[0][r]);
      pa0[r + 4] = (short)f2b(e[1][r]);
      pa1[r]     = (short)f2b(e[2][r]);
      pa1[r + 4] = (short)f2b(e[3][r]);
    }
    #pragma unroll
    for (int nf = 0; nf < 4; nf++) {
      acc_o[nf] = mfma16(pa0, vv0[nf], acc_o[nf]);
      acc_o[nf] = mfma16(pa1, vv1[nf], acc_o[nf]);
    }
  }

  // row sum for q = q0+wrow+lr (4 lanes share lr); inv stays in registers
  lsum += __shfl_xor(lsum, 16);
  lsum += __shfl_xor(lsum, 32);
  float inv = 1.0f / lsum;
  float invr[4];
  #pragma unroll
  for (int r = 0; r < 4; r++) invr[r] = __shfl(inv, rb + r);

  // head = O / l  (bf16)
  unsigned short* hrow = head + ((size_t)(n * 2048 + q0 + wrow)) * 1024 + h * 64;
  #pragma unroll
  for (int nf = 0; nf < 4; nf++)
    #pragma unroll
    for (int r = 0; r < 4; r++)
      hrow[(size_t)(rb + r) * 1024 + nf * 16 + lr] = f2b(acc_o[nf][r] * invr[r]);

  // ---- phase B: streaming energy+attention, no barriers, delayed stores ----
  float* eblk = energy + (size_t)nh * (2048ull * 2048ull) +
                (size_t)(q0 + wrow) * 2048;
  float* ablk = attn + (size_t)nh * (2048ull * 2048ull) +
                (size_t)(q0 + wrow) * 2048;
  float* sb = &stage[w][0];                  // 1024 floats, wave-private
  int colf = lr * 4;                         // extract col (floats)

  f32x4 er[4];                               // previous round's extraction
  int pc0 = 0;
  for (int c0 = 0; c0 < 2048; c0 += 64) {
    // 1) this round's K loads (oldest VMEM of the round)
    s16x8 ka[4], kc[4];
    #pragma unroll
    for (int jk = 0; jk < 4; jk++) {
      const unsigned short* kp = Kb + (size_t)(c0 + jk * 16 + lr) * 1024 + kg;
      ka[jk] = *(const s16x8*)kp;
      kc[jk] = *(const s16x8*)(kp + 32);
    }
    // 2) delayed NT stores of previous round (younger than the loads ->
    //    the MFMA's load-wait never requires these to retire)
    if (c0 > 0) {
      #pragma unroll
      for (int ext = 0; ext < 4; ext++) {
        int row = ext * 4 + g;
        float iv = __shfl(inv, row);
        __builtin_nontemporal_store(
            er[ext], (f32x4*)(eblk + (size_t)row * 2048 + pc0 + colf));
        f32x4 av;
        av[0] = __expf(er[ext][0] * 0.125f) * iv;
        av[1] = __expf(er[ext][1] * 0.125f) * iv;
        av[2] = __expf(er[ext][2] * 0.125f) * iv;
        av[3] = __expf(er[ext][3] * 0.125f) * iv;
        __builtin_nontemporal_store(
            av, (f32x4*)(ablk + (size_t)row * 2048 + pc0 + colf));
      }
      pc0 = c0;
    }
    // 3) QK^T (unpermuted swapped: s[jk][r] = S[k=c0+jk*16+rb+r][q=lr])
    f32x4 s[4];
    #pragma unroll
    for (int jk = 0; jk < 4; jk++) {
      f32x4 z = {};
      z = mfma16(ka[jk], bq0, z);
      s[jk] = mfma16(kc[jk], bq1, z);
    }
    // 4) stage write: [q=lr][kcol], bijective XOR swizzle in 16B units
    #pragma unroll
    for (int jk = 0; jk < 4; jk++) {
      int cf = jk * 16 + rb;
      sb[0]; // keep sb live
      *(f32x4*)&sb[lr * 64 + (cf ^ ((lr & 15) << 2))] = s[jk];
    }
    // 5) extract rows -> registers (stored next round)
    #pragma unroll
    for (int ext = 0; ext < 4; ext++) {
      int row = ext * 4 + g;
      er[ext] = *(const f32x4*)&sb[row * 64 + (colf ^ ((row & 15) << 2))];
    }
  }
  { // epilogue: store last round (pc0 = 1984)
    #pragma unroll
    for (int ext = 0; ext < 4; ext++) {
      int row = ext * 4 + g;
      float iv = __shfl(inv, row);
      __builtin_nontemporal_store(
          er[ext], (f32x4*)(eblk + (size_t)row * 2048 + 1984 + colf));
      f32x4 av;
      av[0] = __expf(er[ext][0] * 0.125f) * iv;
      av[1] = __expf(er[ext][1] * 0.125f) * iv;
      av[2] = __expf(er[ext][2] * 0.125f) * iv;
      av[3] = __expf(er[ext][3] * 0.125f) * iv;
      __builtin_nontemporal_store(
          av, (f32x4*)(ablk + (size_t)row * 2048 + 1984 + colf));
    }
  }
}

// ---------------------------------------------------------------------------
extern "C" void kernel_launch(void* const* d_in, const int* in_sizes, int n_in,
                              void* d_out, int out_size, void* d_ws, size_t ws_size,
                              hipStream_t stream) {
  const float* Vin = (const float*)d_in[0];
  const float* Kin = (const float*)d_in[1];
  const float* Qin = (const float*)d_in[2];
  const float* Wq  = (const float*)d_in[3];
  const float* bq  = (const float*)d_in[4];
  const float* Wk  = (const float*)d_in[5];
  const float* bk  = (const float*)d_in[6];
  const float* Wv  = (const float*)d_in[7];
  const float* bv  = (const float*)d_in[8];
  const float* Wo  = (const float*)d_in[9];
  const float* bo  = (const float*)d_in[10];

  float* out    = (float*)d_out;
  float* qf     = out + 4194304;          // (4096,1024) f32; kf,vf follow
  float* energy = out + 16777216;         // (2,16,2048,2048) f32
  float* attn   = out + 150994944;

  unsigned short* vt = (unsigned short*)out;            // [nh][64][2048]
  unsigned short* kb = (unsigned short*)out + 4194304;
  unsigned short* wqkv = (unsigned short*)energy;
  unsigned short* xqkv = (unsigned short*)(energy + 2097152);
  // d_ws: head bf16 (8MB) + wob bf16 (2MB)
  unsigned short* head = (unsigned short*)d_ws;
  unsigned short* wob  = head + 4194304;

  cvt7_k<<<dim3(2048, 7), 256, 0, stream>>>(
      Wq, Wk, Wv, Wo, Qin, Kin, Vin, wqkv, wob, xqkv);

  gemm_bt<true><<<dim3(8, 32, 3), 256, 0, stream>>>(
      xqkv, wqkv, bq, bk, bv, qf, kb);

  transpose_v_k<<<dim3(32, 32), 256, 0, stream>>>(qf + 8388608, vt);

  attn_fused3_k<<<dim3(1024), 256, 0, stream>>>(qf, kb, vt, energy, attn, head);

  gemm_bt64<<<dim3(16, 32), 256, 0, stream>>>(head, wob, bo, out);
}

// Round 12
// 473.087 us; speedup vs baseline: 1.1280x; 1.0027x over previous
//
#include <hip/hip_runtime.h>

// ---------------------------------------------------------------------------
// SelfAttention forward (N=2, L=2048, E=1024, H=16, D=64), f32 in/out.
// Outputs concatenated: out | q | k | v | energy | attention
//
// Round-12 = round-11 + HBM-channel de-phasing in attention phase B.
// Mechanism: energy/attention rows are 8KB (= multiple of the HBM channel
// interleave period), so every store instruction's row-segments land on ONE
// channel, selected by c0. All waves/blocks were c0-synchronized -> the
// whole GPU stored to one channel slot at a time (~2.1 TB/s measured, r7).
// Fix: per-(block,wave) rotated chunk start: phase=((cid*4+w)&31)*64,
// c0=(phase+it*64)&2047. PV/energy/attention are chunk-order-invariant.
// Everything else byte-identical to round 11.
// ---------------------------------------------------------------------------

typedef __attribute__((ext_vector_type(8))) short     s16x8;   // 8 bf16
typedef __attribute__((ext_vector_type(4))) float     f32x4;
typedef __attribute__((ext_vector_type(8))) unsigned short u16x8;
typedef __attribute__((ext_vector_type(4))) unsigned short u16x4;

#define DEVINL __device__ __forceinline__

DEVINL unsigned short f2b(float f) {           // f32 -> bf16 (RNE)
  unsigned int u = __builtin_bit_cast(unsigned int, f);
  u = (u + 0x7FFFu + ((u >> 16) & 1u)) >> 16;
  return (unsigned short)u;
}

DEVINL s16x8 pack8(float4 a, float4 b) {
  s16x8 r;
  r[0] = (short)f2b(a.x); r[1] = (short)f2b(a.y);
  r[2] = (short)f2b(a.z); r[3] = (short)f2b(a.w);
  r[4] = (short)f2b(b.x); r[5] = (short)f2b(b.y);
  r[6] = (short)f2b(b.z); r[7] = (short)f2b(b.w);
  return r;
}

DEVINL f32x4 mfma16(s16x8 a, s16x8 b, f32x4 c) {
  return __builtin_amdgcn_mfma_f32_16x16x32_bf16(a, b, c, 0, 0, 0);
}

DEVINL void gload16(const void* g, void* l) {  // 16B global -> LDS direct
  __builtin_amdgcn_global_load_lds(
      (const __attribute__((address_space(1))) void*)g,
      (__attribute__((address_space(3))) void*)l, 16, 0, 0);
}

// ---------------------------------------------------------------------------
// 7 f32->bf16 converts in one launch. grid (2048, 7).
// ---------------------------------------------------------------------------
__global__ __launch_bounds__(256) void cvt7_k(
    const float* __restrict__ w0, const float* __restrict__ w1,
    const float* __restrict__ w2, const float* __restrict__ w3,
    const float* __restrict__ x0, const float* __restrict__ x1,
    const float* __restrict__ x2, unsigned short* __restrict__ dw,
    unsigned short* __restrict__ dwo, unsigned short* __restrict__ dx) {
  int z = blockIdx.y;
  const float* s;
  unsigned short* d;
  int n;
  if (z < 3)      { s = (z == 0) ? w0 : (z == 1) ? w1 : w2;
                    d = dw + (size_t)z * 1048576; n = 1048576; }
  else if (z == 3){ s = w3; d = dwo; n = 1048576; }
  else            { s = (z == 4) ? x0 : (z == 5) ? x1 : x2;
                    d = dx + (size_t)(z - 4) * 4194304; n = 4194304; }
  int i = (blockIdx.x * 256 + threadIdx.x) * 8;
  if (i < n) {
    float4 a = *(const float4*)(s + i);
    float4 b = *(const float4*)(s + i + 4);
    u16x8 o;
    o[0] = f2b(a.x); o[1] = f2b(a.y); o[2] = f2b(a.z); o[3] = f2b(a.w);
    o[4] = f2b(b.x); o[5] = f2b(b.y); o[6] = f2b(b.z); o[7] = f2b(b.w);
    *(u16x8*)(d + i) = o;
  }
}

// ---------------------------------------------------------------------------
// m97-style NT GEMM, 128x128 tile (q/k/v projections).
// ---------------------------------------------------------------------------
template<bool QKV>
__global__ __launch_bounds__(256) void gemm_bt(
    const unsigned short* __restrict__ Ab, const unsigned short* __restrict__ Bb,
    const float* __restrict__ b0, const float* __restrict__ b1,
    const float* __restrict__ b2, float* __restrict__ Cf,
    unsigned short* __restrict__ Cb) {
  __shared__ unsigned short lA[4096];   // [128][32] bf16, linear
  __shared__ unsigned short lB[4096];
  int z = QKV ? blockIdx.z : 0;
  const unsigned short* A = Ab + (size_t)z * 4194304;
  const unsigned short* B = Bb + (size_t)z * 1048576;
  const float* bias = (z == 0) ? b0 : (z == 1) ? b1 : b2;
  float* C = Cf + (size_t)z * 4194304;
  unsigned short* Cw = (QKV && z == 1) ? Cb : nullptr;

  int t = threadIdx.x, lane = t & 63, w = t >> 6;
  int m0 = blockIdx.y * 128, n0 = blockIdx.x * 128;
  int wm = (w >> 1) * 64, wn = (w & 1) * 64;
  int lr = lane & 15, g = lane >> 4, kg = g * 8, rb = g * 4;

  int srow = t >> 2, scol = (t & 3) * 8;
  const unsigned short* gA = A + (size_t)(m0 + srow) * 1024 + scol;
  const unsigned short* gB = B + (size_t)(n0 + srow) * 1024 + scol;
  unsigned short* dA = lA + w * 512;
  unsigned short* dB = lB + w * 512;

  f32x4 acc[4][4] = {};

  for (int k0 = 0; k0 < 1024; k0 += 32) {
    gload16(gA,             dA);
    gload16(gA + 64 * 1024, dA + 2048);
    gload16(gB,             dB);
    gload16(gB + 64 * 1024, dB + 2048);
    gA += 32; gB += 32;
    __syncthreads();
    s16x8 af[4], bf[4];
    #pragma unroll
    for (int i = 0; i < 4; i++)
      af[i] = *(const s16x8*)&lA[(wm + i * 16 + lr) * 32 + kg];
    #pragma unroll
    for (int j = 0; j < 4; j++)
      bf[j] = *(const s16x8*)&lB[(wn + j * 16 + lr) * 32 + kg];
    #pragma unroll
    for (int i = 0; i < 4; i++)
      #pragma unroll
      for (int j = 0; j < 4; j++)
        acc[i][j] = mfma16(af[i], bf[j], acc[i][j]);
    __syncthreads();
  }

  #pragma unroll
  for (int i = 0; i < 4; i++) {
    #pragma unroll
    for (int j = 0; j < 4; j++) {
      int col = n0 + wn + j * 16 + lr;
      float bv = bias[col];
      #pragma unroll
      for (int r = 0; r < 4; r++) {
        int row = m0 + wm + i * 16 + rb + r;
        float v = acc[i][j][r] + bv;
        size_t idx = (size_t)row * 1024 + col;
        C[idx] = v;
        if (Cw) Cw[idx] = f2b(v);
      }
    }
  }
}

// ---------------------------------------------------------------------------
// 128x64-tile GEMM for the out-projection: grid (16,32) = 512 blocks.
// ---------------------------------------------------------------------------
__global__ __launch_bounds__(256) void gemm_bt64(
    const unsigned short* __restrict__ Ab, const unsigned short* __restrict__ Bb,
    const float* __restrict__ bias, float* __restrict__ Cf) {
  __shared__ unsigned short lA[4096];   // [128][32]
  __shared__ unsigned short lB[2048];   // [64][32]
  int t = threadIdx.x, lane = t & 63, w = t >> 6;
  int m0 = blockIdx.y * 128, n0 = blockIdx.x * 64;
  int wm = (w >> 1) * 64, wn = (w & 1) * 32;
  int lr = lane & 15, g = lane >> 4, kg = g * 8, rb = g * 4;

  int srow = t >> 2, scol = (t & 3) * 8;
  unsigned short* dA = lA + w * 512;
  unsigned short* dB = lB + w * 512;

  const unsigned short* gA = Ab + (size_t)(m0 + srow) * 1024 + scol;
  const unsigned short* gB = Bb + (size_t)(n0 + srow) * 1024 + scol;
  f32x4 acc[4][2] = {};
  for (int k0 = 0; k0 < 1024; k0 += 32) {
    gload16(gA,             dA);
    gload16(gA + 64 * 1024, dA + 2048);
    gload16(gB,             dB);
    gA += 32; gB += 32;
    __syncthreads();
    s16x8 af[4], bf[2];
    #pragma unroll
    for (int i = 0; i < 4; i++)
      af[i] = *(const s16x8*)&lA[(wm + i * 16 + lr) * 32 + kg];
    #pragma unroll
    for (int j = 0; j < 2; j++)
      bf[j] = *(const s16x8*)&lB[(wn + j * 16 + lr) * 32 + kg];
    #pragma unroll
    for (int i = 0; i < 4; i++)
      #pragma unroll
      for (int j = 0; j < 2; j++)
        acc[i][j] = mfma16(af[i], bf[j], acc[i][j]);
    __syncthreads();
  }
  #pragma unroll
  for (int i = 0; i < 4; i++) {
    #pragma unroll
    for (int j = 0; j < 2; j++) {
      int col = n0 + wn + j * 16 + lr;
      float bv = bias[col];
      #pragma unroll
      for (int r = 0; r < 4; r++) {
        int row = m0 + wm + i * 16 + rb + r;
        Cf[(size_t)row * 1024 + col] = acc[i][j][r] + bv;
      }
    }
  }
}

// ---------------------------------------------------------------------------
// v (f32, [n][l][h*64+d]) -> vt (bf16, [n*16+h][d][l])  (unchanged)
// ---------------------------------------------------------------------------
__global__ __launch_bounds__(256) void transpose_v_k(
    const float* __restrict__ vf, unsigned short* __restrict__ vt) {
  __shared__ unsigned short tile[64][72];
  int nh = blockIdx.y, n = nh >> 4, h = nh & 15;
  int l0 = blockIdx.x * 64;
  int t = threadIdx.x;
  int lr = t >> 2;
  int dc = (t & 3) * 16;
  const float* src = vf + ((size_t)(n * 2048 + l0 + lr)) * 1024 + h * 64 + dc;
  float4 a = *(const float4*)(src);
  float4 b = *(const float4*)(src + 4);
  float4 c = *(const float4*)(src + 8);
  float4 e = *(const float4*)(src + 12);
  float vals[16] = {a.x, a.y, a.z, a.w, b.x, b.y, b.z, b.w,
                    c.x, c.y, c.z, c.w, e.x, e.y, e.z, e.w};
  #pragma unroll
  for (int j = 0; j < 16; j++) tile[dc + j][lr] = f2b(vals[j]);
  __syncthreads();
  int dr = t >> 2;
  int lc = (t & 3) * 16;
  unsigned short* dst = vt + ((size_t)nh * 64 + dr) * 2048 + l0 + lc;
  *(u16x8*)(dst)     = *(const u16x8*)&tile[dr][lc];
  *(u16x8*)(dst + 8) = *(const u16x8*)&tile[dr][lc + 8];
}

// ---------------------------------------------------------------------------
// attn_fused3_k: 1024 blocks x 256 thr (4 waves). Wave w owns q-rows
// q0+w*16 .. +15 end-to-end; everything wave-private; NO barriers.
// Phase B chunk order rotated per (block,wave) for HBM channel spread.
// ---------------------------------------------------------------------------
__global__ __launch_bounds__(256, 4) void attn_fused3_k(
    const float* __restrict__ qf, const unsigned short* __restrict__ kb,
    const unsigned short* __restrict__ vt, float* __restrict__ energy,
    float* __restrict__ attn, unsigned short* __restrict__ head) {
  __shared__ float stage[4][1024];           // 4KB per wave
  int bid = blockIdx.x;
  int cid = (bid & 7) * 128 + (bid >> 3);    // XCD-contiguous remap (1024/8)
  int nh = cid >> 5, qt = cid & 31;
  int n = nh >> 4, h = nh & 15;
  int t = threadIdx.x, w = t >> 6, lane = t & 63;
  int q0 = qt * 64, wrow = w * 16;
  int lr = lane & 15, g = lane >> 4, kg = g * 8, rb = g * 4;
  int kbase = ((lr >> 2) << 3) + (lr & 3);   // tau's lane-row component

  const float* qrow = qf + ((size_t)(n * 2048 + q0 + wrow + lr)) * 1024 + h * 64;
  s16x8 bq0 = pack8(*(const float4*)(qrow + kg), *(const float4*)(qrow + kg + 4));
  s16x8 bq1 = pack8(*(const float4*)(qrow + 32 + kg),
                    *(const float4*)(qrow + 32 + kg + 4));

  const unsigned short* Kb = kb + (size_t)n * (2048 * 1024) + h * 64;
  const unsigned short* Vb = vt + (size_t)nh * (64 * 2048);

  // ---- phase A: compute-only PV + row sums (tau-permuted, no big stores) ----
  float lsum = 0.f;
  f32x4 acc_o[4] = {};
  for (int c0 = 0; c0 < 2048; c0 += 64) {
    s16x8 vv0[4], vv1[4];
    #pragma unroll
    for (int nf = 0; nf < 4; nf++) {
      const unsigned short* vp = Vb + (size_t)(nf * 16 + lr) * 2048 + c0 + kg;
      vv0[nf] = *(const s16x8*)(vp);
      vv1[nf] = *(const s16x8*)(vp + 32);
    }
    f32x4 s[4];
    #pragma unroll
    for (int jk = 0; jk < 4; jk++) {
      int kr = c0 + ((jk >> 1) << 5) + ((jk & 1) << 2) + kbase;
      const unsigned short* kp = Kb + (size_t)kr * 1024 + kg;
      s16x8 a0 = *(const s16x8*)kp;
      s16x8 a1 = *(const s16x8*)(kp + 32);
      f32x4 z = {};
      z = mfma16(a0, bq0, z);
      s[jk] = mfma16(a1, bq1, z);
    }
    float e[4][4];
    #pragma unroll
    for (int jk = 0; jk < 4; jk++)
      #pragma unroll
      for (int r = 0; r < 4; r++) {
        e[jk][r] = __expf(s[jk][r] * 0.125f);
        lsum += e[jk][r];
      }
    s16x8 pa0, pa1;
    #pragma unroll
    for (int r = 0; r < 4; r++) {
      pa0[r]     = (short)f2b(e[0][r]);
      pa0[r + 4] = (short)f2b(e[1][r]);
      pa1[r]     = (short)f2b(e[2][r]);
      pa1[r + 4] = (short)f2b(e[3][r]);
    }
    #pragma unroll
    for (int nf = 0; nf < 4; nf++) {
      acc_o[nf] = mfma16(pa0, vv0[nf], acc_o[nf]);
      acc_o[nf] = mfma16(pa1, vv1[nf], acc_o[nf]);
    }
  }

  // row sum for q = q0+wrow+lr (4 lanes share lr); inv stays in registers
  lsum += __shfl_xor(lsum, 16);
  lsum += __shfl_xor(lsum, 32);
  float inv = 1.0f / lsum;
  float invr[4];
  #pragma unroll
  for (int r = 0; r < 4; r++) invr[r] = __shfl(inv, rb + r);

  // head = O / l  (bf16)
  unsigned short* hrow = head + ((size_t)(n * 2048 + q0 + wrow)) * 1024 + h * 64;
  #pragma unroll
  for (int nf = 0; nf < 4; nf++)
    #pragma unroll
    for (int r = 0; r < 4; r++)
      hrow[(size_t)(rb + r) * 1024 + nf * 16 + lr] = f2b(acc_o[nf][r] * invr[r]);

  // ---- phase B: streaming energy+attention, no barriers, delayed stores,
  //      per-(block,wave) rotated chunk order for channel spread ----
  float* eblk = energy + (size_t)nh * (2048ull * 2048ull) +
                (size_t)(q0 + wrow) * 2048;
  float* ablk = attn + (size_t)nh * (2048ull * 2048ull) +
                (size_t)(q0 + wrow) * 2048;
  float* sb = &stage[w][0];                  // 1024 floats, wave-private
  int colf = lr * 4;                         // extract col (floats)
  int phase = (((cid << 2) + w) & 31) << 6;  // rotated start chunk (floats)

  f32x4 er[4];                               // previous round's extraction
  int pc = -1;
  for (int it = 0; it < 32; ++it) {
    int c0 = (phase + (it << 6)) & 2047;
    // 1) this round's K loads (oldest VMEM of the round)
    s16x8 ka[4], kc[4];
    #pragma unroll
    for (int jk = 0; jk < 4; jk++) {
      const unsigned short* kp = Kb + (size_t)(c0 + jk * 16 + lr) * 1024 + kg;
      ka[jk] = *(const s16x8*)kp;
      kc[jk] = *(const s16x8*)(kp + 32);
    }
    // 2) delayed NT stores of previous round (younger than the loads ->
    //    the MFMA's load-wait never requires these to retire)
    if (pc >= 0) {
      #pragma unroll
      for (int ext = 0; ext < 4; ext++) {
        int row = ext * 4 + g;
        float iv = __shfl(inv, row);
        __builtin_nontemporal_store(
            er[ext], (f32x4*)(eblk + (size_t)row * 2048 + pc + colf));
        f32x4 av;
        av[0] = __expf(er[ext][0] * 0.125f) * iv;
        av[1] = __expf(er[ext][1] * 0.125f) * iv;
        av[2] = __expf(er[ext][2] * 0.125f) * iv;
        av[3] = __expf(er[ext][3] * 0.125f) * iv;
        __builtin_nontemporal_store(
            av, (f32x4*)(ablk + (size_t)row * 2048 + pc + colf));
      }
    }
    // 3) QK^T (unpermuted swapped: s[jk][r] = S[k=c0+jk*16+rb+r][q=lr])
    f32x4 s[4];
    #pragma unroll
    for (int jk = 0; jk < 4; jk++) {
      f32x4 z = {};
      z = mfma16(ka[jk], bq0, z);
      s[jk] = mfma16(kc[jk], bq1, z);
    }
    // 4) stage write: [q=lr][kcol], bijective XOR swizzle in 16B units
    #pragma unroll
    for (int jk = 0; jk < 4; jk++) {
      int cf = jk * 16 + rb;
      *(f32x4*)&sb[lr * 64 + (cf ^ ((lr & 15) << 2))] = s[jk];
    }
    // 5) extract rows -> registers (stored next round)
    #pragma unroll
    for (int ext = 0; ext < 4; ext++) {
      int row = ext * 4 + g;
      er[ext] = *(const f32x4*)&sb[row * 64 + (colf ^ ((row & 15) << 2))];
    }
    pc = c0;
  }
  { // epilogue: store last round
    #pragma unroll
    for (int ext = 0; ext < 4; ext++) {
      int row = ext * 4 + g;
      float iv = __shfl(inv, row);
      __builtin_nontemporal_store(
          er[ext], (f32x4*)(eblk + (size_t)row * 2048 + pc + colf));
      f32x4 av;
      av[0] = __expf(er[ext][0] * 0.125f) * iv;
      av[1] = __expf(er[ext][1] * 0.125f) * iv;
      av[2] = __expf(er[ext][2] * 0.125f) * iv;
      av[3] = __expf(er[ext][3] * 0.125f) * iv;
      __builtin_nontemporal_store(
          av, (f32x4*)(ablk + (size_t)row * 2048 + pc + colf));
    }
  }
}

// ---------------------------------------------------------------------------
extern "C" void kernel_launch(void* const* d_in, const int* in_sizes, int n_in,
                              void* d_out, int out_size, void* d_ws, size_t ws_size,
                              hipStream_t stream) {
  const float* Vin = (const float*)d_in[0];
  const float* Kin = (const float*)d_in[1];
  const float* Qin = (const float*)d_in[2];
  const float* Wq  = (const float*)d_in[3];
  const float* bq  = (const float*)d_in[4];
  const float* Wk  = (const float*)d_in[5];
  const float* bk  = (const float*)d_in[6];
  const float* Wv  = (const float*)d_in[7];
  const float* bv  = (const float*)d_in[8];
  const float* Wo  = (const float*)d_in[9];
  const float* bo  = (const float*)d_in[10];

  float* out    = (float*)d_out;
  float* qf     = out + 4194304;          // (4096,1024) f32; kf,vf follow
  float* energy = out + 16777216;         // (2,16,2048,2048) f32
  float* attn   = out + 150994944;

  unsigned short* vt = (unsigned short*)out;            // [nh][64][2048]
  unsigned short* kb = (unsigned short*)out + 4194304;
  unsigned short* wqkv = (unsigned short*)energy;
  unsigned short* xqkv = (unsigned short*)(energy + 2097152);
  // d_ws: head bf16 (8MB) + wob bf16 (2MB)
  unsigned short* head = (unsigned short*)d_ws;
  unsigned short* wob  = head + 4194304;

  cvt7_k<<<dim3(2048, 7), 256, 0, stream>>>(
      Wq, Wk, Wv, Wo, Qin, Kin, Vin, wqkv, wob, xqkv);

  gemm_bt<true><<<dim3(8, 32, 3), 256, 0, stream>>>(
      xqkv, wqkv, bq, bk, bv, qf, kb);

  transpose_v_k<<<dim3(32, 32), 256, 0, stream>>>(qf + 8388608, vt);

  attn_fused3_k<<<dim3(1024), 256, 0, stream>>>(qf, kb, vt, energy, attn, head);

  gemm_bt64<<<dim3(16, 32), 256, 0, stream>>>(head, wob, bo, out);
}

// Round 13
// 454.012 us; speedup vs baseline: 1.1753x; 1.0420x over previous
//
#include <hip/hip_runtime.h>

// ---------------------------------------------------------------------------
// SelfAttention forward (N=2, L=2048, E=1024, H=16, D=64), f32 in/out.
// Outputs concatenated: out | q | k | v | energy | attention
//
// Round-13: attn kernel restructured to OVERLAP PV compute with energy
// stores (round-6's winning property) while keeping tau lane-local P
// (round 8), delayed vmcnt-FIFO-safe NT stores and the bijective stage
// swizzle (rounds 11/12). Zero barriers, wave-private 4KB stages.
//  Pass 1 per 64-col chunk: K loads (tau) -> V loads -> delayed NT energy
//    store of prev chunk -> QK^T -> tau-aware stage write (stage holds
//    STANDARD [q][k] layout) -> exp + lane-local P -> PV -> extract.
//  Pass 2: QK^T recompute -> exp*inv applied before stage write (inv is
//    lane-local) -> same delayed-store pipeline for attention.
// Everything else identical to round 12.
// ---------------------------------------------------------------------------

typedef __attribute__((ext_vector_type(8))) short     s16x8;   // 8 bf16
typedef __attribute__((ext_vector_type(4))) float     f32x4;
typedef __attribute__((ext_vector_type(8))) unsigned short u16x8;
typedef __attribute__((ext_vector_type(4))) unsigned short u16x4;

#define DEVINL __device__ __forceinline__

DEVINL unsigned short f2b(float f) {           // f32 -> bf16 (RNE)
  unsigned int u = __builtin_bit_cast(unsigned int, f);
  u = (u + 0x7FFFu + ((u >> 16) & 1u)) >> 16;
  return (unsigned short)u;
}

DEVINL s16x8 pack8(float4 a, float4 b) {
  s16x8 r;
  r[0] = (short)f2b(a.x); r[1] = (short)f2b(a.y);
  r[2] = (short)f2b(a.z); r[3] = (short)f2b(a.w);
  r[4] = (short)f2b(b.x); r[5] = (short)f2b(b.y);
  r[6] = (short)f2b(b.z); r[7] = (short)f2b(b.w);
  return r;
}

DEVINL f32x4 mfma16(s16x8 a, s16x8 b, f32x4 c) {
  return __builtin_amdgcn_mfma_f32_16x16x32_bf16(a, b, c, 0, 0, 0);
}

DEVINL void gload16(const void* g, void* l) {  // 16B global -> LDS direct
  __builtin_amdgcn_global_load_lds(
      (const __attribute__((address_space(1))) void*)g,
      (__attribute__((address_space(3))) void*)l, 16, 0, 0);
}

// ---------------------------------------------------------------------------
// 7 f32->bf16 converts in one launch. grid (2048, 7).
// ---------------------------------------------------------------------------
__global__ __launch_bounds__(256) void cvt7_k(
    const float* __restrict__ w0, const float* __restrict__ w1,
    const float* __restrict__ w2, const float* __restrict__ w3,
    const float* __restrict__ x0, const float* __restrict__ x1,
    const float* __restrict__ x2, unsigned short* __restrict__ dw,
    unsigned short* __restrict__ dwo, unsigned short* __restrict__ dx) {
  int z = blockIdx.y;
  const float* s;
  unsigned short* d;
  int n;
  if (z < 3)      { s = (z == 0) ? w0 : (z == 1) ? w1 : w2;
                    d = dw + (size_t)z * 1048576; n = 1048576; }
  else if (z == 3){ s = w3; d = dwo; n = 1048576; }
  else            { s = (z == 4) ? x0 : (z == 5) ? x1 : x2;
                    d = dx + (size_t)(z - 4) * 4194304; n = 4194304; }
  int i = (blockIdx.x * 256 + threadIdx.x) * 8;
  if (i < n) {
    float4 a = *(const float4*)(s + i);
    float4 b = *(const float4*)(s + i + 4);
    u16x8 o;
    o[0] = f2b(a.x); o[1] = f2b(a.y); o[2] = f2b(a.z); o[3] = f2b(a.w);
    o[4] = f2b(b.x); o[5] = f2b(b.y); o[6] = f2b(b.z); o[7] = f2b(b.w);
    *(u16x8*)(d + i) = o;
  }
}

// ---------------------------------------------------------------------------
// m97-style NT GEMM, 128x128 tile (q/k/v projections).
// ---------------------------------------------------------------------------
template<bool QKV>
__global__ __launch_bounds__(256) void gemm_bt(
    const unsigned short* __restrict__ Ab, const unsigned short* __restrict__ Bb,
    const float* __restrict__ b0, const float* __restrict__ b1,
    const float* __restrict__ b2, float* __restrict__ Cf,
    unsigned short* __restrict__ Cb) {
  __shared__ unsigned short lA[4096];   // [128][32] bf16, linear
  __shared__ unsigned short lB[4096];
  int z = QKV ? blockIdx.z : 0;
  const unsigned short* A = Ab + (size_t)z * 4194304;
  const unsigned short* B = Bb + (size_t)z * 1048576;
  const float* bias = (z == 0) ? b0 : (z == 1) ? b1 : b2;
  float* C = Cf + (size_t)z * 4194304;
  unsigned short* Cw = (QKV && z == 1) ? Cb : nullptr;

  int t = threadIdx.x, lane = t & 63, w = t >> 6;
  int m0 = blockIdx.y * 128, n0 = blockIdx.x * 128;
  int wm = (w >> 1) * 64, wn = (w & 1) * 64;
  int lr = lane & 15, g = lane >> 4, kg = g * 8, rb = g * 4;

  int srow = t >> 2, scol = (t & 3) * 8;
  const unsigned short* gA = A + (size_t)(m0 + srow) * 1024 + scol;
  const unsigned short* gB = B + (size_t)(n0 + srow) * 1024 + scol;
  unsigned short* dA = lA + w * 512;
  unsigned short* dB = lB + w * 512;

  f32x4 acc[4][4] = {};

  for (int k0 = 0; k0 < 1024; k0 += 32) {
    gload16(gA,             dA);
    gload16(gA + 64 * 1024, dA + 2048);
    gload16(gB,             dB);
    gload16(gB + 64 * 1024, dB + 2048);
    gA += 32; gB += 32;
    __syncthreads();
    s16x8 af[4], bf[4];
    #pragma unroll
    for (int i = 0; i < 4; i++)
      af[i] = *(const s16x8*)&lA[(wm + i * 16 + lr) * 32 + kg];
    #pragma unroll
    for (int j = 0; j < 4; j++)
      bf[j] = *(const s16x8*)&lB[(wn + j * 16 + lr) * 32 + kg];
    #pragma unroll
    for (int i = 0; i < 4; i++)
      #pragma unroll
      for (int j = 0; j < 4; j++)
        acc[i][j] = mfma16(af[i], bf[j], acc[i][j]);
    __syncthreads();
  }

  #pragma unroll
  for (int i = 0; i < 4; i++) {
    #pragma unroll
    for (int j = 0; j < 4; j++) {
      int col = n0 + wn + j * 16 + lr;
      float bv = bias[col];
      #pragma unroll
      for (int r = 0; r < 4; r++) {
        int row = m0 + wm + i * 16 + rb + r;
        float v = acc[i][j][r] + bv;
        size_t idx = (size_t)row * 1024 + col;
        C[idx] = v;
        if (Cw) Cw[idx] = f2b(v);
      }
    }
  }
}

// ---------------------------------------------------------------------------
// 128x64-tile GEMM for the out-projection: grid (16,32) = 512 blocks.
// ---------------------------------------------------------------------------
__global__ __launch_bounds__(256) void gemm_bt64(
    const unsigned short* __restrict__ Ab, const unsigned short* __restrict__ Bb,
    const float* __restrict__ bias, float* __restrict__ Cf) {
  __shared__ unsigned short lA[4096];   // [128][32]
  __shared__ unsigned short lB[2048];   // [64][32]
  int t = threadIdx.x, lane = t & 63, w = t >> 6;
  int m0 = blockIdx.y * 128, n0 = blockIdx.x * 64;
  int wm = (w >> 1) * 64, wn = (w & 1) * 32;
  int lr = lane & 15, g = lane >> 4, kg = g * 8, rb = g * 4;

  int srow = t >> 2, scol = (t & 3) * 8;
  unsigned short* dA = lA + w * 512;
  unsigned short* dB = lB + w * 512;

  const unsigned short* gA = Ab + (size_t)(m0 + srow) * 1024 + scol;
  const unsigned short* gB = Bb + (size_t)(n0 + srow) * 1024 + scol;
  f32x4 acc[4][2] = {};
  for (int k0 = 0; k0 < 1024; k0 += 32) {
    gload16(gA,             dA);
    gload16(gA + 64 * 1024, dA + 2048);
    gload16(gB,             dB);
    gA += 32; gB += 32;
    __syncthreads();
    s16x8 af[4], bf[2];
    #pragma unroll
    for (int i = 0; i < 4; i++)
      af[i] = *(const s16x8*)&lA[(wm + i * 16 + lr) * 32 + kg];
    #pragma unroll
    for (int j = 0; j < 2; j++)
      bf[j] = *(const s16x8*)&lB[(wn + j * 16 + lr) * 32 + kg];
    #pragma unroll
    for (int i = 0; i < 4; i++)
      #pragma unroll
      for (int j = 0; j < 2; j++)
        acc[i][j] = mfma16(af[i], bf[j], acc[i][j]);
    __syncthreads();
  }
  #pragma unroll
  for (int i = 0; i < 4; i++) {
    #pragma unroll
    for (int j = 0; j < 2; j++) {
      int col = n0 + wn + j * 16 + lr;
      float bv = bias[col];
      #pragma unroll
      for (int r = 0; r < 4; r++) {
        int row = m0 + wm + i * 16 + rb + r;
        Cf[(size_t)row * 1024 + col] = acc[i][j][r] + bv;
      }
    }
  }
}

// ---------------------------------------------------------------------------
// v (f32, [n][l][h*64+d]) -> vt (bf16, [n*16+h][d][l])  (unchanged)
// ---------------------------------------------------------------------------
__global__ __launch_bounds__(256) void transpose_v_k(
    const float* __restrict__ vf, unsigned short* __restrict__ vt) {
  __shared__ unsigned short tile[64][72];
  int nh = blockIdx.y, n = nh >> 4, h = nh & 15;
  int l0 = blockIdx.x * 64;
  int t = threadIdx.x;
  int lr = t >> 2;
  int dc = (t & 3) * 16;
  const float* src = vf + ((size_t)(n * 2048 + l0 + lr)) * 1024 + h * 64 + dc;
  float4 a = *(const float4*)(src);
  float4 b = *(const float4*)(src + 4);
  float4 c = *(const float4*)(src + 8);
  float4 e = *(const float4*)(src + 12);
  float vals[16] = {a.x, a.y, a.z, a.w, b.x, b.y, b.z, b.w,
                    c.x, c.y, c.z, c.w, e.x, e.y, e.z, e.w};
  #pragma unroll
  for (int j = 0; j < 16; j++) tile[dc + j][lr] = f2b(vals[j]);
  __syncthreads();
  int dr = t >> 2;
  int lc = (t & 3) * 16;
  unsigned short* dst = vt + ((size_t)nh * 64 + dr) * 2048 + l0 + lc;
  *(u16x8*)(dst)     = *(const u16x8*)&tile[dr][lc];
  *(u16x8*)(dst + 8) = *(const u16x8*)&tile[dr][lc + 8];
}

// ---------------------------------------------------------------------------
// attn_fused4_k: 1024 blocks x 256 thr (4 waves). Wave w owns q-rows
// q0+w*16..+15; wave-private 4KB stage; NO barriers.
// tau: lane (g,lr), frag jk holds S[q=lr][k = c0+(jk>>1)*32+g*8+(jk&1)*4+r].
// Stage write uses the same tau col -> stage holds STANDARD [q][k] tile;
// extraction (row=ext*4+g, cols lr*4..+3) is row-contiguous for stores.
// ---------------------------------------------------------------------------
__global__ __launch_bounds__(256, 3) void attn_fused4_k(
    const float* __restrict__ qf, const unsigned short* __restrict__ kb,
    const unsigned short* __restrict__ vt, float* __restrict__ energy,
    float* __restrict__ attn, unsigned short* __restrict__ head) {
  __shared__ float stage[4][1024];           // 4KB per wave
  int bid = blockIdx.x;
  int cid = (bid & 7) * 128 + (bid >> 3);    // XCD-contiguous remap (1024/8)
  int nh = cid >> 5, qt = cid & 31;
  int n = nh >> 4, h = nh & 15;
  int t = threadIdx.x, w = t >> 6, lane = t & 63;
  int q0 = qt * 64, wrow = w * 16;
  int lr = lane & 15, g = lane >> 4, kg = g * 8, rb = g * 4;
  int kbase = ((lr >> 2) << 3) + (lr & 3);   // tau's lane-row component

  const float* qrow = qf + ((size_t)(n * 2048 + q0 + wrow + lr)) * 1024 + h * 64;
  s16x8 bq0 = pack8(*(const float4*)(qrow + kg), *(const float4*)(qrow + kg + 4));
  s16x8 bq1 = pack8(*(const float4*)(qrow + 32 + kg),
                    *(const float4*)(qrow + 32 + kg + 4));

  const unsigned short* Kb = kb + (size_t)n * (2048 * 1024) + h * 64;
  const unsigned short* Vb = vt + (size_t)nh * (64 * 2048);
  float* eblk = energy + (size_t)nh * (2048ull * 2048ull) +
                (size_t)(q0 + wrow) * 2048;
  float* ablk = attn + (size_t)nh * (2048ull * 2048ull) +
                (size_t)(q0 + wrow) * 2048;
  float* sb = &stage[w][0];                  // 1024 floats, wave-private
  int colf = lr * 4;                         // extract col (floats)

  // ---- pass 1: energy stores (delayed) overlapped with exp + PV ----
  float lsum = 0.f;
  f32x4 acc_o[4] = {};
  f32x4 er[4];
  int pc = -1;
  for (int c0 = 0; c0 < 2048; c0 += 64) {
    // 1) K loads, tau order (oldest VMEM of the round)
    s16x8 ka[4], kc[4];
    #pragma unroll
    for (int jk = 0; jk < 4; jk++) {
      int kr = c0 + ((jk >> 1) << 5) + ((jk & 1) << 2) + kbase;
      const unsigned short* kp = Kb + (size_t)kr * 1024 + kg;
      ka[jk] = *(const s16x8*)kp;
      kc[jk] = *(const s16x8*)(kp + 32);
    }
    // 2) V loads
    s16x8 vv0[4], vv1[4];
    #pragma unroll
    for (int nf = 0; nf < 4; nf++) {
      const unsigned short* vp = Vb + (size_t)(nf * 16 + lr) * 2048 + c0 + kg;
      vv0[nf] = *(const s16x8*)(vp);
      vv1[nf] = *(const s16x8*)(vp + 32);
    }
    // 3) delayed NT energy stores of previous chunk (younger than the loads
    //    -> the MFMA's load-wait never requires these to retire)
    if (pc >= 0) {
      #pragma unroll
      for (int ext = 0; ext < 4; ext++) {
        int row = ext * 4 + g;
        __builtin_nontemporal_store(
            er[ext], (f32x4*)(eblk + (size_t)row * 2048 + pc + colf));
      }
    }
    // 4) QK^T (tau layout)
    f32x4 s[4];
    #pragma unroll
    for (int jk = 0; jk < 4; jk++) {
      f32x4 z = {};
      z = mfma16(ka[jk], bq0, z);
      s[jk] = mfma16(kc[jk], bq1, z);
    }
    // 5) stage write with tau col -> standard-layout tile in stage
    #pragma unroll
    for (int jk = 0; jk < 4; jk++) {
      int col = ((jk >> 1) << 5) + kg + ((jk & 1) << 2);
      *(f32x4*)&sb[lr * 64 + (col ^ ((lr & 15) << 2))] = s[jk];
    }
    // 6) exp + lane-local P (tau) + PV
    float e[4][4];
    #pragma unroll
    for (int jk = 0; jk < 4; jk++)
      #pragma unroll
      for (int r = 0; r < 4; r++) {
        e[jk][r] = __expf(s[jk][r] * 0.125f);
        lsum += e[jk][r];
      }
    s16x8 pa0, pa1;
    #pragma unroll
    for (int r = 0; r < 4; r++) {
      pa0[r]     = (short)f2b(e[0][r]);
      pa0[r + 4] = (short)f2b(e[1][r]);
      pa1[r]     = (short)f2b(e[2][r]);
      pa1[r + 4] = (short)f2b(e[3][r]);
    }
    #pragma unroll
    for (int nf = 0; nf < 4; nf++) {
      acc_o[nf] = mfma16(pa0, vv0[nf], acc_o[nf]);
      acc_o[nf] = mfma16(pa1, vv1[nf], acc_o[nf]);
    }
    // 7) extract rows -> registers (stored next round)
    #pragma unroll
    for (int ext = 0; ext < 4; ext++) {
      int row = ext * 4 + g;
      er[ext] = *(const f32x4*)&sb[row * 64 + (colf ^ ((row & 15) << 2))];
    }
    pc = c0;
  }
  { // epilogue: store last chunk's energy
    #pragma unroll
    for (int ext = 0; ext < 4; ext++) {
      int row = ext * 4 + g;
      __builtin_nontemporal_store(
          er[ext], (f32x4*)(eblk + (size_t)row * 2048 + pc + colf));
    }
  }

  // row sum for q = q0+wrow+lr (4 lanes share lr); inv stays in registers
  lsum += __shfl_xor(lsum, 16);
  lsum += __shfl_xor(lsum, 32);
  float inv = 1.0f / lsum;
  float invr[4];
  #pragma unroll
  for (int r = 0; r < 4; r++) invr[r] = __shfl(inv, rb + r);

  // head = O / l  (bf16)
  unsigned short* hrow = head + ((size_t)(n * 2048 + q0 + wrow)) * 1024 + h * 64;
  #pragma unroll
  for (int nf = 0; nf < 4; nf++)
    #pragma unroll
    for (int r = 0; r < 4; r++)
      hrow[(size_t)(rb + r) * 1024 + nf * 16 + lr] = f2b(acc_o[nf][r] * invr[r]);

  // ---- pass 2: attention = exp(s/8)*inv, exp*inv applied pre-stage ----
  pc = -1;
  for (int c0 = 0; c0 < 2048; c0 += 64) {
    s16x8 ka[4], kc[4];
    #pragma unroll
    for (int jk = 0; jk < 4; jk++) {
      int kr = c0 + ((jk >> 1) << 5) + ((jk & 1) << 2) + kbase;
      const unsigned short* kp = Kb + (size_t)kr * 1024 + kg;
      ka[jk] = *(const s16x8*)kp;
      kc[jk] = *(const s16x8*)(kp + 32);
    }
    if (pc >= 0) {
      #pragma unroll
      for (int ext = 0; ext < 4; ext++) {
        int row = ext * 4 + g;
        __builtin_nontemporal_store(
            er[ext], (f32x4*)(ablk + (size_t)row * 2048 + pc + colf));
      }
    }
    f32x4 s[4];
    #pragma unroll
    for (int jk = 0; jk < 4; jk++) {
      f32x4 z = {};
      z = mfma16(ka[jk], bq0, z);
      s[jk] = mfma16(kc[jk], bq1, z);
    }
    // exp*inv lane-local (q = lr), then stage in standard layout
    #pragma unroll
    for (int jk = 0; jk < 4; jk++) {
      f32x4 av;
      av[0] = __expf(s[jk][0] * 0.125f) * inv;
      av[1] = __expf(s[jk][1] * 0.125f) * inv;
      av[2] = __expf(s[jk][2] * 0.125f) * inv;
      av[3] = __expf(s[jk][3] * 0.125f) * inv;
      int col = ((jk >> 1) << 5) + kg + ((jk & 1) << 2);
      *(f32x4*)&sb[lr * 64 + (col ^ ((lr & 15) << 2))] = av;
    }
    #pragma unroll
    for (int ext = 0; ext < 4; ext++) {
      int row = ext * 4 + g;
      er[ext] = *(const f32x4*)&sb[row * 64 + (colf ^ ((row & 15) << 2))];
    }
    pc = c0;
  }
  { // epilogue: store last chunk's attention
    #pragma unroll
    for (int ext = 0; ext < 4; ext++) {
      int row = ext * 4 + g;
      __builtin_nontemporal_store(
          er[ext], (f32x4*)(ablk + (size_t)row * 2048 + pc + colf));
    }
  }
}

// ---------------------------------------------------------------------------
extern "C" void kernel_launch(void* const* d_in, const int* in_sizes, int n_in,
                              void* d_out, int out_size, void* d_ws, size_t ws_size,
                              hipStream_t stream) {
  const float* Vin = (const float*)d_in[0];
  const float* Kin = (const float*)d_in[1];
  const float* Qin = (const float*)d_in[2];
  const float* Wq  = (const float*)d_in[3];
  const float* bq  = (const float*)d_in[4];
  const float* Wk  = (const float*)d_in[5];
  const float* bk  = (const float*)d_in[6];
  const float* Wv  = (const float*)d_in[7];
  const float* bv  = (const float*)d_in[8];
  const float* Wo  = (const float*)d_in[9];
  const float* bo  = (const float*)d_in[10];

  float* out    = (float*)d_out;
  float* qf     = out + 4194304;          // (4096,1024) f32; kf,vf follow
  float* energy = out + 16777216;         // (2,16,2048,2048) f32
  float* attn   = out + 150994944;

  unsigned short* vt = (unsigned short*)out;            // [nh][64][2048]
  unsigned short* kb = (unsigned short*)out + 4194304;
  unsigned short* wqkv = (unsigned short*)energy;
  unsigned short* xqkv = (unsigned short*)(energy + 2097152);
  // d_ws: head bf16 (8MB) + wob bf16 (2MB)
  unsigned short* head = (unsigned short*)d_ws;
  unsigned short* wob  = head + 4194304;

  cvt7_k<<<dim3(2048, 7), 256, 0, stream>>>(
      Wq, Wk, Wv, Wo, Qin, Kin, Vin, wqkv, wob, xqkv);

  gemm_bt<true><<<dim3(8, 32, 3), 256, 0, stream>>>(
      xqkv, wqkv, bq, bk, bv, qf, kb);

  transpose_v_k<<<dim3(32, 32), 256, 0, stream>>>(qf + 8388608, vt);

  attn_fused4_k<<<dim3(1024), 256, 0, stream>>>(qf, kb, vt, energy, attn, head);

  gemm_bt64<<<dim3(16, 32), 256, 0, stream>>>(head, wob, bo, out);
}